// Round 8
// baseline (48.454 us; speedup 1.0000x reference)
//
#include <hip/hip_runtime.h>
#include <math.h>

#define N_T    16384
#define BLOCK  1024
#define NCH    4          // chunks per row; chunk = 4096 elems
#define CHSZ   4096
#define NWAVE  16

// Workgroup barrier that only drains LDS ops (all our cross-thread data is
// LDS-resident). Avoids __syncthreads()'s implicit vmcnt(0) drain, so global
// loads issued early stay in flight across barriers.
__device__ __forceinline__ void barrier_lgkm() {
    asm volatile("s_waitcnt lgkmcnt(0)" ::: "memory");
    __builtin_amdgcn_s_barrier();
}

// MODE 0: d_out = real part only, flat (16,64,16384) float32  (out_size = N)
// MODE 1: d_out = interleaved re/im pairs                     (out_size = 2N)
template <int MODE>
__global__ __launch_bounds__(BLOCK)
void phase_kernel(const float* __restrict__ x, float* __restrict__ out) {
    // 1 KiB of LDS total — occupancy limited only by VGPRs
    __shared__ float rawEdge[NCH][NWAVE];  // raw .w of lane63, per chunk/wave
    __shared__ int   wtot[NCH][NWAVE];     // wave-inclusive jump totals
    __shared__ float corrR[NCH][NWAVE];    // corrected .w of lane63
    __shared__ float corrL[NCH][NWAVE];    // corrected .x of lane0

    const int tid  = threadIdx.x;
    const int lane = tid & 63;
    const int wv   = tid >> 6;
    const int r    = blockIdx.x;          // row in [0, 1024)
    const int b    = r >> 6;
    const int c    = r & 63;
    const float* __restrict__ phase_row = x + ((size_t)(b * 128 + 64 + c)) * N_T;
    const float* __restrict__ mag_row   = x + ((size_t)(b * 128 + c)) * N_T;

    const float TWO_PI = 6.28318530717958647692f;  // f32 0x40C90FDB
    const float PI_F   = 3.14159265358979323846f;
    const float THIRD  = 1.0f / 3.0f;

    // ---- 1. coalesced register loads: phase first (critical path), then mag.
    //         With lgkm-only barriers the mag loads stay in flight through the
    //         whole scan; the compiler's vmcnt(N) before first use is the only
    //         wait they ever see.
    float s[16];
    #pragma unroll
    for (int i = 0; i < NCH; ++i) {
        float4 v = *reinterpret_cast<const float4*>(phase_row + i * CHSZ + tid * 4);
        s[i * 4 + 0] = v.x; s[i * 4 + 1] = v.y;
        s[i * 4 + 2] = v.z; s[i * 4 + 3] = v.w;
    }
    float4 mg[NCH];
    #pragma unroll
    for (int i = 0; i < NCH; ++i)
        mg[i] = *reinterpret_cast<const float4*>(mag_row + i * CHSZ + tid * 4);

    // publish raw wave-edge values (lane63's .w per chunk)
    if (lane == 63) {
        #pragma unroll
        for (int i = 0; i < NCH; ++i) rawEdge[i][wv] = s[i * 4 + 3];
    }
    barrier_lgkm();                                    // barrier A

    // raw element just before each chunk-segment of this thread
    float prevRaw[NCH];
    #pragma unroll
    for (int i = 0; i < NCH; ++i) {
        float p = __shfl_up(s[i * 4 + 3], 1);
        if (lane == 0) {
            if (wv > 0)      p = rawEdge[i][wv - 1];
            else if (i > 0)  p = rawEdge[i - 1][NWAVE - 1];
            else             p = 0.0f;                 // t==0: d forced 0 below
        }
        prevRaw[i] = p;
    }

    // ---- 2. per-chunk local jump-counts (4 elements each)
    int lsum[NCH];
    #pragma unroll
    for (int i = 0; i < NCH; ++i) {
        float prev = prevRaw[i];
        int cnt = 0;
        #pragma unroll
        for (int k = 0; k < 4; ++k) {
            float cur = s[i * 4 + k];
            float g = cur - prev;
            bool first = (i == 0 && tid == 0 && k == 0);
            if (!first && fabsf(g) > 0.5f) cnt += (g > 0.0f) ? 1 : -1;
            prev = cur;
        }
        lsum[i] = cnt;
    }

    // ---- 3. four parallel wave-inclusive scans, then cross-wave/chunk prefix
    int incl[NCH] = {lsum[0], lsum[1], lsum[2], lsum[3]};
    #pragma unroll
    for (int off = 1; off < 64; off <<= 1) {
        #pragma unroll
        for (int i = 0; i < NCH; ++i) {
            int n = __shfl_up(incl[i], off);
            if (lane >= off) incl[i] += n;
        }
    }
    if (lane == 63) {
        #pragma unroll
        for (int i = 0; i < NCH; ++i) wtot[i][wv] = incl[i];
    }
    barrier_lgkm();                                    // barrier B

    int P[NCH];
    {
        int chunkPre = 0;
        #pragma unroll
        for (int i = 0; i < NCH; ++i) {
            int wpre = 0, tot = 0;
            #pragma unroll
            for (int w = 0; w < NWAVE; ++w) {
                int t = wtot[i][w];                    // wave-uniform broadcast
                if (w < wv) wpre += t;
                tot += t;
            }
            P[i] = chunkPre + wpre + (incl[i] - lsum[i]);  // exclusive prefix
            chunkPre += tot;
        }
    }

    // ---- 4. corrected phase in place
    #pragma unroll
    for (int i = 0; i < NCH; ++i) {
        int running = P[i];
        float prev = prevRaw[i];
        #pragma unroll
        for (int k = 0; k < 4; ++k) {
            float cur = s[i * 4 + k];
            int d = 0;
            bool first = (i == 0 && tid == 0 && k == 0);
            if (!first) {
                float g = cur - prev;
                if (fabsf(g) > 0.5f) d = (g > 0.0f) ? 1 : -1;
            }
            s[i * 4 + k] = (cur - (float)running) * TWO_PI - PI_F;
            running += d;
            prev = cur;
        }
    }

    // publish corrected edges
    if (lane == 63) {
        #pragma unroll
        for (int i = 0; i < NCH; ++i) corrR[i][wv] = s[i * 4 + 3];
    }
    if (lane == 0) {
        #pragma unroll
        for (int i = 0; i < NCH; ++i) corrL[i][wv] = s[i * 4 + 0];
    }
    barrier_lgkm();                                    // barrier C

    // ---- 5. smooth + blend + range-reduced cos/sin + coalesced store
    #pragma unroll
    for (int i = 0; i < NCH; ++i) {
        float left = __shfl_up(s[i * 4 + 3], 1);
        if (lane == 0) {
            if (wv > 0)      left = corrR[i][wv - 1];
            else if (i > 0)  left = corrR[i - 1][NWAVE - 1];
            else             left = 0.0f;              // zero pad at t==0
        }
        float right = __shfl_down(s[i * 4 + 0], 1);
        if (lane == 63) {
            if (wv < NWAVE - 1)  right = corrL[i][wv + 1];
            else if (i < NCH - 1) right = corrL[i + 1][0];
            else                  right = 0.0f;        // zero pad at t==N-1
        }

        float mgk[4] = {mg[i].x, mg[i].y, mg[i].z, mg[i].w};
        float re[4], im[4];
        #pragma unroll
        for (int k = 0; k < 4; ++k) {
            float pm = (k == 0) ? left  : s[i * 4 + k - 1];
            float pp = (k == 3) ? right : s[i * 4 + k + 1];
            float cur = s[i * 4 + k];
            float sm = ((pm + cur) + pp) * THIRD;
            float pf = 0.7f * cur + 0.3f * sm;
            // two-term range reduction: 2pi = hi + lo
            float nrev = rintf(pf * 0.15915494309189535f);
            float rr = fmaf(nrev, -6.28318548202514648f, pf);
            rr = fmaf(nrev, 1.74845553e-7f, rr);
            re[k] = mgk[k] * __cosf(rr);
            if (MODE == 1) im[k] = mgk[k] * __sinf(rr);
        }
        if (MODE == 0) {
            float* o = out + (size_t)r * N_T + i * CHSZ + tid * 4;
            *reinterpret_cast<float4*>(o) = make_float4(re[0], re[1], re[2], re[3]);
        } else {
            float* o = out + (size_t)r * (2 * N_T) + 2 * (i * CHSZ + tid * 4);
            *reinterpret_cast<float4*>(o)     = make_float4(re[0], im[0], re[1], im[1]);
            *reinterpret_cast<float4*>(o + 4) = make_float4(re[2], im[2], re[3], im[3]);
        }
    }
}

extern "C" void kernel_launch(void* const* d_in, const int* in_sizes, int n_in,
                              void* d_out, int out_size, void* d_ws, size_t ws_size,
                              hipStream_t stream) {
    const float* x = (const float*)d_in[0];
    float* out = (float*)d_out;
    int n_rows = in_sizes[0] / (2 * N_T);              // 1024
    if (out_size >= in_sizes[0]) {
        phase_kernel<1><<<n_rows, BLOCK, 0, stream>>>(x, out);
    } else {
        phase_kernel<0><<<n_rows, BLOCK, 0, stream>>>(x, out);
    }
}

// Round 9
// 43.444 us; speedup vs baseline: 1.1153x; 1.1153x over previous
//
#include <hip/hip_runtime.h>
#include <math.h>

#define N_T    16384
#define BLOCK  1024
#define NCH    4          // chunks per row; chunk = 4096 elems
#define CHSZ   4096
#define NWAVE  16

// Workgroup barrier that only drains LDS ops. Avoids __syncthreads()'s
// implicit vmcnt(0) drain, so global loads issued earlier stay in flight.
__device__ __forceinline__ void barrier_lgkm() {
    asm volatile("s_waitcnt lgkmcnt(0)" ::: "memory");
    __builtin_amdgcn_s_barrier();
}

// MODE 0: d_out = real part only, flat (16,64,16384) float32  (out_size = N)
// MODE 1: d_out = interleaved re/im pairs                     (out_size = 2N)
template <int MODE>
__global__ __launch_bounds__(BLOCK)
void phase_kernel(const float* __restrict__ x, float* __restrict__ out) {
    // 1 KiB of LDS total — occupancy limited only by VGPRs
    __shared__ float rawEdge[NCH][NWAVE];  // raw .w of lane63, per chunk/wave
    __shared__ int   wtot[NCH][NWAVE];     // wave-inclusive jump totals
    __shared__ float corrR[NCH][NWAVE];    // corrected .w of lane63
    __shared__ float corrL[NCH][NWAVE];    // corrected .x of lane0

    const int tid  = threadIdx.x;
    const int lane = tid & 63;
    const int wv   = tid >> 6;
    const int r    = blockIdx.x;          // row in [0, 1024)
    const int b    = r >> 6;
    const int c    = r & 63;
    const float* __restrict__ phase_row = x + ((size_t)(b * 128 + 64 + c)) * N_T;
    const float* __restrict__ mag_row   = x + ((size_t)(b * 128 + c)) * N_T;

    const float TWO_PI = 6.28318530717958647692f;  // f32 0x40C90FDB
    const float PI_F   = 3.14159265358979323846f;
    const float THIRD  = 1.0f / 3.0f;

    // ---- 1. coalesced register load: chunk i, elements i*4096 + tid*4 .. +3
    float s[16];
    #pragma unroll
    for (int i = 0; i < NCH; ++i) {
        float4 v = *reinterpret_cast<const float4*>(phase_row + i * CHSZ + tid * 4);
        s[i * 4 + 0] = v.x; s[i * 4 + 1] = v.y;
        s[i * 4 + 2] = v.z; s[i * 4 + 3] = v.w;
    }

    // publish raw wave-edge values (lane63's .w per chunk)
    if (lane == 63) {
        #pragma unroll
        for (int i = 0; i < NCH; ++i) rawEdge[i][wv] = s[i * 4 + 3];
    }
    __syncthreads();                                   // barrier A (vmcnt drain
                                                       // free: phase consumed)

    // ---- mag prefetch: issued AFTER the critical phase loads are consumed,
    //      hides under the scan; never drained (barriers B/C are lgkm-only),
    //      first wait is the counted vmcnt before use in phase 5.
    float4 mg[NCH];
    #pragma unroll
    for (int i = 0; i < NCH; ++i)
        mg[i] = *reinterpret_cast<const float4*>(mag_row + i * CHSZ + tid * 4);

    // raw element just before each chunk-segment of this thread
    float prevRaw[NCH];
    #pragma unroll
    for (int i = 0; i < NCH; ++i) {
        float p = __shfl_up(s[i * 4 + 3], 1);
        if (lane == 0) {
            if (wv > 0)      p = rawEdge[i][wv - 1];
            else if (i > 0)  p = rawEdge[i - 1][NWAVE - 1];
            else             p = 0.0f;                 // t==0: d forced 0 below
        }
        prevRaw[i] = p;
    }

    // ---- 2. per-chunk local jump-counts (4 elements each)
    int lsum[NCH];
    #pragma unroll
    for (int i = 0; i < NCH; ++i) {
        float prev = prevRaw[i];
        int cnt = 0;
        #pragma unroll
        for (int k = 0; k < 4; ++k) {
            float cur = s[i * 4 + k];
            float g = cur - prev;
            bool first = (i == 0 && tid == 0 && k == 0);
            if (!first && fabsf(g) > 0.5f) cnt += (g > 0.0f) ? 1 : -1;
            prev = cur;
        }
        lsum[i] = cnt;
    }

    // ---- 3. four parallel wave-inclusive scans, then cross-wave/chunk prefix
    int incl[NCH] = {lsum[0], lsum[1], lsum[2], lsum[3]};
    #pragma unroll
    for (int off = 1; off < 64; off <<= 1) {
        #pragma unroll
        for (int i = 0; i < NCH; ++i) {
            int n = __shfl_up(incl[i], off);
            if (lane >= off) incl[i] += n;
        }
    }
    if (lane == 63) {
        #pragma unroll
        for (int i = 0; i < NCH; ++i) wtot[i][wv] = incl[i];
    }
    barrier_lgkm();                                    // barrier B (no vm drain)

    int P[NCH];
    {
        int chunkPre = 0;
        #pragma unroll
        for (int i = 0; i < NCH; ++i) {
            int wpre = 0, tot = 0;
            #pragma unroll
            for (int w = 0; w < NWAVE; ++w) {
                int t = wtot[i][w];                    // wave-uniform broadcast
                if (w < wv) wpre += t;
                tot += t;
            }
            P[i] = chunkPre + wpre + (incl[i] - lsum[i]);  // exclusive prefix
            chunkPre += tot;
        }
    }

    // ---- 4. corrected phase in place
    #pragma unroll
    for (int i = 0; i < NCH; ++i) {
        int running = P[i];
        float prev = prevRaw[i];
        #pragma unroll
        for (int k = 0; k < 4; ++k) {
            float cur = s[i * 4 + k];
            int d = 0;
            bool first = (i == 0 && tid == 0 && k == 0);
            if (!first) {
                float g = cur - prev;
                if (fabsf(g) > 0.5f) d = (g > 0.0f) ? 1 : -1;
            }
            s[i * 4 + k] = (cur - (float)running) * TWO_PI - PI_F;
            running += d;
            prev = cur;
        }
    }

    // publish corrected edges
    if (lane == 63) {
        #pragma unroll
        for (int i = 0; i < NCH; ++i) corrR[i][wv] = s[i * 4 + 3];
    }
    if (lane == 0) {
        #pragma unroll
        for (int i = 0; i < NCH; ++i) corrL[i][wv] = s[i * 4 + 0];
    }
    barrier_lgkm();                                    // barrier C (no vm drain)

    // ---- 5. smooth + blend + range-reduced cos/sin + coalesced store
    #pragma unroll
    for (int i = 0; i < NCH; ++i) {
        float left = __shfl_up(s[i * 4 + 3], 1);
        if (lane == 0) {
            if (wv > 0)      left = corrR[i][wv - 1];
            else if (i > 0)  left = corrR[i - 1][NWAVE - 1];
            else             left = 0.0f;              // zero pad at t==0
        }
        float right = __shfl_down(s[i * 4 + 0], 1);
        if (lane == 63) {
            if (wv < NWAVE - 1)  right = corrL[i][wv + 1];
            else if (i < NCH - 1) right = corrL[i + 1][0];
            else                  right = 0.0f;        // zero pad at t==N-1
        }

        float mgk[4] = {mg[i].x, mg[i].y, mg[i].z, mg[i].w};
        float re[4], im[4];
        #pragma unroll
        for (int k = 0; k < 4; ++k) {
            float pm = (k == 0) ? left  : s[i * 4 + k - 1];
            float pp = (k == 3) ? right : s[i * 4 + k + 1];
            float cur = s[i * 4 + k];
            float sm = ((pm + cur) + pp) * THIRD;
            float pf = 0.7f * cur + 0.3f * sm;
            // two-term range reduction: 2pi = hi + lo
            float nrev = rintf(pf * 0.15915494309189535f);
            float rr = fmaf(nrev, -6.28318548202514648f, pf);
            rr = fmaf(nrev, 1.74845553e-7f, rr);
            re[k] = mgk[k] * __cosf(rr);
            if (MODE == 1) im[k] = mgk[k] * __sinf(rr);
        }
        if (MODE == 0) {
            float* o = out + (size_t)r * N_T + i * CHSZ + tid * 4;
            *reinterpret_cast<float4*>(o) = make_float4(re[0], re[1], re[2], re[3]);
        } else {
            float* o = out + (size_t)r * (2 * N_T) + 2 * (i * CHSZ + tid * 4);
            *reinterpret_cast<float4*>(o)     = make_float4(re[0], im[0], re[1], im[1]);
            *reinterpret_cast<float4*>(o + 4) = make_float4(re[2], im[2], re[3], im[3]);
        }
    }
}

extern "C" void kernel_launch(void* const* d_in, const int* in_sizes, int n_in,
                              void* d_out, int out_size, void* d_ws, size_t ws_size,
                              hipStream_t stream) {
    const float* x = (const float*)d_in[0];
    float* out = (float*)d_out;
    int n_rows = in_sizes[0] / (2 * N_T);              // 1024
    if (out_size >= in_sizes[0]) {
        phase_kernel<1><<<n_rows, BLOCK, 0, stream>>>(x, out);
    } else {
        phase_kernel<0><<<n_rows, BLOCK, 0, stream>>>(x, out);
    }
}